// Round 4
// baseline (301.708 us; speedup 1.0000x reference)
//
#include <hip/hip_runtime.h>

typedef float f4 __attribute__((ext_vector_type(4)));

#define EV_G 64            // events per 16-lane group (contiguous, sorted)
#define NG   4             // groups per wave
#define EPW  (EV_G * NG)   // 256 events per wave
#define WPB  4             // waves per block (256 threads)

// Zero exactly the rows that receive atomicAdd flushes: first/last target of
// every group's contiguous 64-event span. 16 lanes zero one 256 B row (f4).
__global__ __launch_bounds__(256) void prezero_kernel(
    const int* __restrict__ acd0, float* __restrict__ out, int ngroups, int M)
{
    const int task = blockIdx.x * 16 + (threadIdx.x >> 4);
    const int s    = threadIdx.x & 15;
    if (task >= 2 * ngroups) return;
    long m = (long)(task >> 1) * EV_G + ((task & 1) ? (EV_G - 1) : 0);
    if (m >= M) m = M - 1;
    const int t = acd0[m];
    f4 z = {0.f, 0.f, 0.f, 0.f};
    __builtin_nontemporal_store(z, (f4*)(out + (size_t)t * 64 + s * 4));
}

__global__ __launch_bounds__(256, 4) void spspmm_seg_kernel(
    const float* __restrict__ Aval,   // [NNZ_A, 64]
    const float* __restrict__ Bval,   // [NNZ_B]
    const int*   __restrict__ acd0,   // [M] sorted target idx
    const int*   __restrict__ acd1,   // [M] A row idx
    const int*   __restrict__ acd2,   // [M] B idx
    float*       __restrict__ out,    // [TAR, 64]
    int M, int TAR)
{
    const int lane = threadIdx.x & 63;
    const int s    = lane & 15;           // sublane: channels [s*4, s*4+4)
    const int g    = lane >> 4;           // group within wave
    const int wid  = blockIdx.x * WPB + (threadIdx.x >> 6);
    const long gm0 = (long)wid * EPW + (long)g * EV_G;
    if (gm0 >= M) return;
    const long gEnd = (gm0 + EV_G < (long)M) ? gm0 + EV_G : (long)M;
    const int  nev  = (int)(gEnd - gm0);

    const f4 z4 = {0.f, 0.f, 0.f, 0.f};

    const int t_first = acd0[gm0];
    const int t_prev  = (gm0 > 0) ? acd0[gm0 - 1] : -1;
    // Leading gap: targets with no events between prev event's target and ours.
    for (int t = t_prev + 1; t < t_first; ++t)
        __builtin_nontemporal_store(z4, (f4*)(out + (size_t)t * 64 + s * 4));

    f4  acc   = z4;
    int cur_t = t_first;

    auto flush = [&](int next_t) {
        float* p = out + (size_t)cur_t * 64 + s * 4;
        if (cur_t == t_first) {            // span boundary -> atomic (pre-zeroed)
            atomicAdd(p + 0, acc[0]); atomicAdd(p + 1, acc[1]);
            atomicAdd(p + 2, acc[2]); atomicAdd(p + 3, acc[3]);
        } else {                           // group-exclusive interior row
            __builtin_nontemporal_store(acc, (f4*)p);
        }
        for (int tz = cur_t + 1; tz < next_t; ++tz)   // interior empty rows
            __builtin_nontemporal_store(z4, (f4*)(out + (size_t)tz * 64 + s * 4));
        acc   = z4;
        cur_t = next_t;
    };

    if (nev == EV_G) {
        #pragma unroll 1
        for (int c = 0; c < EV_G / 16; ++c) {
            const long mb = gm0 + c * 16;
            // Coalesced descriptor load: lane s holds event mb+s of its group.
            const int   t_i = __builtin_nontemporal_load(acd0 + mb + s);
            const int   a_i = __builtin_nontemporal_load(acd1 + mb + s);
            const float b_i = Bval[__builtin_nontemporal_load(acd2 + mb + s)];
            // 16 gathers batched: one wave instruction fetches 4 rows (1 KB).
            f4 v[16];
            #pragma unroll
            for (int j = 0; j < 16; ++j) {
                const int a = __shfl(a_i, j, 16);
                v[j] = *(const f4*)(Aval + (size_t)a * 64 + s * 4);
            }
            // Segment scan (group-uniform control flow).
            #pragma unroll
            for (int j = 0; j < 16; ++j) {
                const int   t  = __shfl(t_i, j, 16);
                const float bv = __shfl(b_i, j, 16);
                if (t != cur_t) flush(t);
                acc += v[j] * bv;
            }
        }
    } else {
        // Tail span (not hit when M % EPW == 0): per-event broadcast loads.
        for (int m = 0; m < nev; ++m) {
            const int   t  = acd0[gm0 + m];
            const int   a  = acd1[gm0 + m];
            const float bv = Bval[acd2[gm0 + m]];
            const f4    v  = *(const f4*)(Aval + (size_t)a * 64 + s * 4);
            if (t != cur_t) flush(t);
            acc += v * bv;
        }
    }

    // Final segment may continue into the next group -> atomic (pre-zeroed).
    {
        float* p = out + (size_t)cur_t * 64 + s * 4;
        atomicAdd(p + 0, acc[0]); atomicAdd(p + 1, acc[1]);
        atomicAdd(p + 2, acc[2]); atomicAdd(p + 3, acc[3]);
    }

    // Trailing gap after the very last event's target.
    if (gEnd == M) {
        const int tl = acd0[M - 1];
        for (int t = tl + 1; t < TAR; ++t)
            __builtin_nontemporal_store(z4, (f4*)(out + (size_t)t * 64 + s * 4));
    }
}

extern "C" void kernel_launch(void* const* d_in, const int* in_sizes, int n_in,
                              void* d_out, int out_size, void* d_ws, size_t ws_size,
                              hipStream_t stream) {
    const float* Aval = (const float*)d_in[0];
    const float* Bval = (const float*)d_in[1];
    const int*   acd0 = (const int*)d_in[2];
    const int*   acd1 = (const int*)d_in[3];
    const int*   acd2 = (const int*)d_in[4];
    float* out = (float*)d_out;
    const int M   = in_sizes[2];
    const int TAR = out_size / 64;

    const int ngroups = (M + EV_G - 1) / EV_G;

    // Pre-zero only the atomic-target rows (~33 MB instead of 256 MB memset).
    {
        const int tasks  = 2 * ngroups;
        const int blocks = (tasks + 15) / 16;
        prezero_kernel<<<dim3(blocks), dim3(256), 0, stream>>>(acd0, out, ngroups, M);
    }

    const long nwaves = ((long)M + EPW - 1) / EPW;
    const long blocks = (nwaves + WPB - 1) / WPB;
    spspmm_seg_kernel<<<dim3((unsigned)blocks), dim3(WPB * 64), 0, stream>>>(
        Aval, Bval, acd0, acd1, acd2, out, M, TAR);
}